// Round 16
// baseline (261.498 us; speedup 1.0000x reference)
//
#include <hip/hip_runtime.h>
#include <hip/hip_bf16.h>
#include <stdint.h>

// ---------------------------------------------------------------------------
// UpdateSpeaker: GRU-like gating block.
//   r,p,z = sigmoid(X@Wx*^T + S@Wh*^T + A@Vh*^T)
//   h~    = tanh(X@Wxh^T + (r*S)@Whh^T + (p*A)@Vhh^T)
//   out   = (1-z)*S + z*h~
// Final consolidation:
// GEMM1: R14 exact — 128x128 BK=32 2-phase dbuf, 32 KiB LDS -> 4 blocks/CU
//        (cross-block barrier-domain overlap = the session's main lever),
//        XCD-chunked L2 mapping, Keff (h-gate K=1024), 2-way swizzle.
// GEMM2: SAME structure applied (was 1 blk/CU): 128x128 BK=32, 4 blk/CU,
//        512 blocks all co-resident, final epilogue (S read bf16 from U).
// Packs: U+W1 merged; W2 tiny separate. (HBM floor.)
// ---------------------------------------------------------------------------

typedef short  short8  __attribute__((ext_vector_type(8)));
typedef unsigned short ushort8 __attribute__((ext_vector_type(8)));
typedef float  f32x4   __attribute__((ext_vector_type(4)));

static constexpr int Bn  = 16384;  // batch

__device__ __forceinline__ unsigned short f2bf(float x) {
  union { float f; unsigned u; } v; v.f = x;
  unsigned r = v.u + 0x7fffu + ((v.u >> 16) & 1u);   // RNE
  return (unsigned short)(r >> 16);
}
__device__ __forceinline__ float bf2f(unsigned short h) {
  union { unsigned u; float f; } v; v.u = ((unsigned)h) << 16; return v.f;
}
__device__ __forceinline__ float sigm(float x) { return 1.0f / (1.0f + __expf(-x)); }
__device__ __forceinline__ float tanh_fast(float x) {
  return 2.0f / (1.0f + __expf(-2.0f * x)) - 1.0f;
}

__device__ __forceinline__ void gload_lds16(const void* g, void* l) {
  __builtin_amdgcn_global_load_lds((const __attribute__((address_space(1))) void*)g,
                                   (__attribute__((address_space(3))) void*)l,
                                   16, 0, 0);
}

// ---- merged packing: blocks [0,16384) = U, [16384,18432) = W1 -------------
__global__ __launch_bounds__(256) void pack_all(
    const float* __restrict__ X, const float* __restrict__ S, const float* __restrict__ A,
    const float* __restrict__ xr, const float* __restrict__ xp,
    const float* __restrict__ xz, const float* __restrict__ xh,
    const float* __restrict__ hr, const float* __restrict__ hp, const float* __restrict__ hz,
    const float* __restrict__ vr, const float* __restrict__ vp, const float* __restrict__ vz,
    unsigned short* __restrict__ U, unsigned short* __restrict__ W1)
{
  const int bid = blockIdx.x;
  const int tid = threadIdx.x;
  if (bid < 16384) {
    int idx = bid * 256 + tid;
    int b  = idx >> 8;
    int c8 = (idx & 255) << 3;
    const float* src = (c8 < 1024) ? X + (size_t)b * 1024 + c8
                     : (c8 < 1536) ? S + (size_t)b * 512 + (c8 - 1024)
                                   : A + (size_t)b * 512 + (c8 - 1536);
    f32x4 lo = *(const f32x4*)src;
    f32x4 hi = *(const f32x4*)(src + 4);
    ushort8 o;
    o[0] = f2bf(lo[0]); o[1] = f2bf(lo[1]); o[2] = f2bf(lo[2]); o[3] = f2bf(lo[3]);
    o[4] = f2bf(hi[0]); o[5] = f2bf(hi[1]); o[6] = f2bf(hi[2]); o[7] = f2bf(hi[3]);
    *(ushort8*)&U[(size_t)b * 2048 + c8] = o;
  } else {
    int idx = (bid - 16384) * 256 + tid;
    int n  = idx >> 8;
    int k8 = (idx & 255) << 3;
    int g = n >> 9, j = n & 511;
    const float* src = nullptr;
    if (k8 < 1024) {
      const float* x = (g == 0) ? xr : (g == 1) ? xp : (g == 2) ? xz : xh;
      src = x + (size_t)j * 1024 + k8;
    } else if (k8 < 1536) {
      if (g < 3) { const float* h = (g == 0) ? hr : (g == 1) ? hp : hz; src = h + (size_t)j * 512 + (k8 - 1024); }
    } else {
      if (g < 3) { const float* v = (g == 0) ? vr : (g == 1) ? vp : vz; src = v + (size_t)j * 512 + (k8 - 1536); }
    }
    ushort8 o;
    if (src) { for (int i = 0; i < 8; i++) o[i] = f2bf(src[i]); }
    else     { for (int i = 0; i < 8; i++) o[i] = 0; }
    *(ushort8*)&W1[(size_t)n * 2048 + k8] = o;
  }
}

__global__ __launch_bounds__(256) void pack_w2k(
    const float* __restrict__ hh, const float* __restrict__ vh,
    unsigned short* __restrict__ W2)
{
  int idx = blockIdx.x * 256 + threadIdx.x;
  int n  = idx >> 7;
  int k8 = (idx & 127) << 3;
  const float* src = (k8 < 512) ? hh + (size_t)n * 512 + k8
                                : vh + (size_t)n * 512 + (k8 - 512);
  ushort8 o;
  for (int i = 0; i < 8; i++) o[i] = f2bf(src[i]);
  *(ushort8*)&W2[(size_t)n * 1024 + k8] = o;
}

// ---- GEMM1: 128x128, BK=32, 4 waves (2x2 of 64x64), 2-phase dbuf ----------
// 32 KiB static LDS -> 4 blocks/CU (4 independent barrier domains, m114).
// Swizzle: LDS(row, slot) holds global (row, slot ^ ((row>>1)&3)) -> 2-way.
__global__ __launch_bounds__(256, 4) void gemm128_epi1(
    const unsigned short* __restrict__ Amat,
    const unsigned short* __restrict__ Bmat,
    const int K,
    unsigned short* __restrict__ U2, unsigned short* __restrict__ Zp,
    unsigned short* __restrict__ XHp)
{
  __shared__ __align__(16) char lds[32768];   // 2 buf x (A 8K + B 8K)

  const int tid  = threadIdx.x;
  const int lane = tid & 63, wave = tid >> 6;
  const int wr = wave >> 1, wc = wave & 1;     // 2 x 2 wave grid
  const int fr = lane & 15, fq = lane >> 4;

  // XCD-chunked: XCD k owns m-panels 16k..16k+15, all 16 n-panels.
  const int k_xcd = blockIdx.x & 7;
  const int i_loc = (int)blockIdx.x >> 3;      // 0..255
  const int n0 = (i_loc & 15) * 128;
  const int m0 = (k_xcd * 16 + (i_loc >> 4)) * 128;

  // h-gate panels (ncol>=1536): W1 rows zero for k>=1024 -> truncate K.
  const int Keff = (n0 >= 1536) ? 1024 : K;
  const int NT   = Keff >> 5;                  // K-tiles of 32

  const int srow  = tid >> 2;                  // 0..63
  const int sslot = (tid & 3) ^ ((srow >> 1) & 3);
  const unsigned short* gA = Amat + (size_t)(m0 + srow) * K + sslot * 8;
  const unsigned short* gB = Bmat + (size_t)(n0 + srow) * K + sslot * 8;
  const size_t K64r = (size_t)64 * K;

  const int swz  = (fq ^ ((fr >> 1) & 3)) << 4;
  const int aoff = (wr * 64 + fr) * 64 + swz;         // + mt*1024
  const int boff = 8192 + (wc * 64 + fr) * 64 + swz;  // + nt*1024

  f32x4 acc[4][4] = {};

  auto STAGE = [&](int buf, int tile) {   // 4 gload_lds16 per thread
    const int bufo = buf << 14;
#pragma unroll
    for (int j = 0; j < 2; j++) {
      gload_lds16(gA + (size_t)j * K64r + (tile << 5), lds + bufo + j * 4096 + tid * 16);
      gload_lds16(gB + (size_t)j * K64r + (tile << 5), lds + bufo + 8192 + j * 4096 + tid * 16);
    }
  };
  auto COMPUTE = [&](int buf) {
    const int bufo = buf << 14;
    short8 b[4], a[4];
#pragma unroll
    for (int nt = 0; nt < 4; nt++)
      b[nt] = *(const short8*)(lds + bufo + boff + nt * 1024);
#pragma unroll
    for (int mt = 0; mt < 4; mt++)
      a[mt] = *(const short8*)(lds + bufo + aoff + mt * 1024);
#pragma unroll
    for (int mt = 0; mt < 4; mt++)
#pragma unroll
      for (int nt = 0; nt < 4; nt++)
        acc[mt][nt] = __builtin_amdgcn_mfma_f32_16x16x32_bf16(
            a[mt], b[nt], acc[mt][nt], 0, 0, 0);
  };

  STAGE(0, 0);
  __syncthreads();

  int cur = 0;
  for (int t = 0; t < NT - 1; ++t) {
    STAGE(cur ^ 1, t + 1);
    COMPUTE(cur);
    __syncthreads();
    cur ^= 1;
  }
  COMPUTE(cur);

  // ---- epilogue: fused gate split; S/A read as bf16 from U columns ----
#pragma unroll
  for (int mt = 0; mt < 4; mt++) {
#pragma unroll
    for (int nt = 0; nt < 4; nt++) {
      const int ncol = n0 + wc * 64 + nt * 16 + fr;
      const int gate = ncol >> 9, j = ncol & 511;
#pragma unroll
      for (int jj = 0; jj < 4; jj++) {
        const size_t rb = (size_t)(m0 + wr * 64 + mt * 16 + fq * 4 + jj);
        const float v = acc[mt][nt][jj];
        if (gate == 0) {
          const float s = bf2f(Amat[rb * 2048 + 1024 + j]);   // S (bf16, in U)
          U2[rb * 1024 + j] = f2bf(sigm(v) * s);
        } else if (gate == 1) {
          const float a2 = bf2f(Amat[rb * 2048 + 1536 + j]);  // A (bf16, in U)
          U2[rb * 1024 + 512 + j] = f2bf(sigm(v) * a2);
        } else if (gate == 2) {
          Zp[rb * 512 + j]  = f2bf(v);
        } else {
          XHp[rb * 512 + j] = f2bf(v);
        }
      }
    }
  }
}

// ---- GEMM2: SAME 128x128 BK=32 4-blk/CU structure, final epilogue ---------
// K=1024 fixed; 512 blocks = 8 XCD x (16 m-panels x 4 n-panels), all
// co-resident (512 <= 1024 capacity at 4 blk/CU).
__global__ __launch_bounds__(256, 4) void gemm2_fin128(
    const unsigned short* __restrict__ U2,     // A: B x 1024
    const unsigned short* __restrict__ W2,     // B: 512 x 1024
    const unsigned short* __restrict__ Uu,     // U (S bf16 at cols 1024..1535)
    const unsigned short* __restrict__ Zp,
    const unsigned short* __restrict__ XHp, float* __restrict__ Out)
{
  __shared__ __align__(16) char lds[32768];
  constexpr int K = 1024, NT = K >> 5;         // 32 K-tiles

  const int tid  = threadIdx.x;
  const int lane = tid & 63, wave = tid >> 6;
  const int wr = wave >> 1, wc = wave & 1;
  const int fr = lane & 15, fq = lane >> 4;

  const int k_xcd = blockIdx.x & 7;
  const int i_loc = (int)blockIdx.x >> 3;      // 0..63
  const int n0 = (i_loc & 3) * 128;
  const int m0 = (k_xcd * 16 + (i_loc >> 2)) * 128;

  const int srow  = tid >> 2;                  // 0..63
  const int sslot = (tid & 3) ^ ((srow >> 1) & 3);
  const unsigned short* gA = U2 + (size_t)(m0 + srow) * K + sslot * 8;
  const unsigned short* gB = W2 + (size_t)(n0 + srow) * K + sslot * 8;
  const size_t K64r = (size_t)64 * K;

  const int swz  = (fq ^ ((fr >> 1) & 3)) << 4;
  const int aoff = (wr * 64 + fr) * 64 + swz;
  const int boff = 8192 + (wc * 64 + fr) * 64 + swz;

  f32x4 acc[4][4] = {};

  auto STAGE = [&](int buf, int tile) {
    const int bufo = buf << 14;
#pragma unroll
    for (int j = 0; j < 2; j++) {
      gload_lds16(gA + (size_t)j * K64r + (tile << 5), lds + bufo + j * 4096 + tid * 16);
      gload_lds16(gB + (size_t)j * K64r + (tile << 5), lds + bufo + 8192 + j * 4096 + tid * 16);
    }
  };
  auto COMPUTE = [&](int buf) {
    const int bufo = buf << 14;
    short8 b[4], a[4];
#pragma unroll
    for (int nt = 0; nt < 4; nt++)
      b[nt] = *(const short8*)(lds + bufo + boff + nt * 1024);
#pragma unroll
    for (int mt = 0; mt < 4; mt++)
      a[mt] = *(const short8*)(lds + bufo + aoff + mt * 1024);
#pragma unroll
    for (int mt = 0; mt < 4; mt++)
#pragma unroll
      for (int nt = 0; nt < 4; nt++)
        acc[mt][nt] = __builtin_amdgcn_mfma_f32_16x16x32_bf16(
            a[mt], b[nt], acc[mt][nt], 0, 0, 0);
  };

  STAGE(0, 0);
  __syncthreads();

  int cur = 0;
  for (int t = 0; t < NT - 1; ++t) {
    STAGE(cur ^ 1, t + 1);
    COMPUTE(cur);
    __syncthreads();
    cur ^= 1;
  }
  COMPUTE(cur);

  // ---- final epilogue: out = (1-z)*S + z*tanh(xh + acc) ----
#pragma unroll
  for (int mt = 0; mt < 4; mt++) {
#pragma unroll
    for (int nt = 0; nt < 4; nt++) {
      const int ncol = n0 + wc * 64 + nt * 16 + fr;
#pragma unroll
      for (int jj = 0; jj < 4; jj++) {
        const size_t rb = (size_t)(m0 + wr * 64 + mt * 16 + fq * 4 + jj);
        const size_t o = rb * 512 + ncol;
        const float z = sigm(bf2f(Zp[o]));
        const float h = tanh_fast(bf2f(XHp[o]) + acc[mt][nt][jj]);
        const float s = bf2f(Uu[rb * 2048 + 1024 + ncol]);
        Out[o] = (1.0f - z) * s + z * h;
      }
    }
  }
}

// ---------------------------------------------------------------------------

extern "C" void kernel_launch(void* const* d_in, const int* in_sizes, int n_in,
                              void* d_out, int out_size, void* d_ws, size_t ws_size,
                              hipStream_t stream) {
  const float* X   = (const float*)d_in[0];
  const float* S   = (const float*)d_in[1];
  const float* A   = (const float*)d_in[2];
  const float* Wxr = (const float*)d_in[3];
  const float* Wxp = (const float*)d_in[4];
  const float* Wxz = (const float*)d_in[5];
  const float* Wxh = (const float*)d_in[6];
  const float* Whr = (const float*)d_in[7];
  const float* Whp = (const float*)d_in[8];
  const float* Whz = (const float*)d_in[9];
  const float* Whh = (const float*)d_in[10];
  const float* Vhr = (const float*)d_in[11];
  const float* Vhp = (const float*)d_in[12];
  const float* Vhz = (const float*)d_in[13];
  const float* Vhh = (const float*)d_in[14];

  char* ws = (char*)d_ws;
  size_t off = 0;
  auto alloc = [&](size_t bytes) -> void* {
    void* p = ws + off;
    off += (bytes + 255) & ~(size_t)255;
    return p;
  };
  unsigned short* W1 = (unsigned short*)alloc((size_t)2048 * 2048 * 2);
  unsigned short* W2 = (unsigned short*)alloc((size_t)512 * 1024 * 2);
  unsigned short* U  = (unsigned short*)alloc((size_t)Bn * 2048 * 2);
  unsigned short* U2 = (unsigned short*)alloc((size_t)Bn * 1024 * 2);
  unsigned short* Zp = (unsigned short*)alloc((size_t)Bn * 512 * 2);
  unsigned short* XH = (unsigned short*)alloc((size_t)Bn * 512 * 2);

  pack_all<<<16384 + 2048, 256, 0, stream>>>(
      X, S, A, Wxr, Wxp, Wxz, Wxh, Whr, Whp, Whz, Vhr, Vhp, Vhz, U, W1);
  pack_w2k<<<256, 256, 0, stream>>>(Whh, Vhh, W2);

  // GEMM1: P = U(16384x2048) @ W1^T(2048x2048), gate epilogue.
  // Grid 2048 = 8 XCD x (16 m-panels x 16 n-panels); 4 blocks/CU.
  gemm128_epi1<<<2048, 256, 0, stream>>>(U, W1, 2048, U2, Zp, XH);

  // GEMM2: U2(16384x1024) @ W2^T(512x1024), final epilogue -> d_out.
  // Grid 512 = 8 XCD x (16 m-panels x 4 n-panels); 4 blocks/CU, one round.
  gemm2_fin128<<<512, 256, 0, stream>>>(U2, W2, U, Zp, XH, (float*)d_out);
}

// Round 17
// 238.088 us; speedup vs baseline: 1.0983x; 1.0983x over previous
//
#include <hip/hip_runtime.h>
#include <hip/hip_bf16.h>
#include <stdint.h>

// ---------------------------------------------------------------------------
// UpdateSpeaker: GRU-like gating block.
//   r,p,z = sigmoid(X@Wx*^T + S@Wh*^T + A@Vh*^T)
//   h~    = tanh(X@Wxh^T + (r*S)@Whh^T + (p*A)@Vhh^T)
//   out   = (1-z)*S + z*h~
// FINAL (R13 config, best graded total 239.6us):
// GEMM1: 128x128 BK=64 2-phase dbuf, 64 KiB LDS -> 2 blocks/CU (cross-block
//        barrier-domain overlap), XCD-chunked L2 mapping, Keff, 8-slot swizzle.
// GEMM2: 256x128 BK=64 2-phase, 256 blocks = 1/CU single round.
// Packs: ALL THREE merged into one dispatch (U | W1 | W2).
// ---------------------------------------------------------------------------

typedef short  short8  __attribute__((ext_vector_type(8)));
typedef unsigned short ushort8 __attribute__((ext_vector_type(8)));
typedef float  f32x4   __attribute__((ext_vector_type(4)));

static constexpr int Bn  = 16384;  // batch

__device__ __forceinline__ unsigned short f2bf(float x) {
  union { float f; unsigned u; } v; v.f = x;
  unsigned r = v.u + 0x7fffu + ((v.u >> 16) & 1u);   // RNE
  return (unsigned short)(r >> 16);
}
__device__ __forceinline__ float bf2f(unsigned short h) {
  union { unsigned u; float f; } v; v.u = ((unsigned)h) << 16; return v.f;
}
__device__ __forceinline__ float sigm(float x) { return 1.0f / (1.0f + __expf(-x)); }
__device__ __forceinline__ float tanh_fast(float x) {
  return 2.0f / (1.0f + __expf(-2.0f * x)) - 1.0f;
}

__device__ __forceinline__ void gload_lds16(const void* g, void* l) {
  __builtin_amdgcn_global_load_lds((const __attribute__((address_space(1))) void*)g,
                                   (__attribute__((address_space(3))) void*)l,
                                   16, 0, 0);
}

// ---- merged packing: [0,16384)=U, [16384,18432)=W1, [18432,18688)=W2 ------
__global__ __launch_bounds__(256) void pack_all(
    const float* __restrict__ X, const float* __restrict__ S, const float* __restrict__ A,
    const float* __restrict__ xr, const float* __restrict__ xp,
    const float* __restrict__ xz, const float* __restrict__ xh,
    const float* __restrict__ hr, const float* __restrict__ hp, const float* __restrict__ hz,
    const float* __restrict__ vr, const float* __restrict__ vp, const float* __restrict__ vz,
    const float* __restrict__ hh, const float* __restrict__ vh,
    unsigned short* __restrict__ U, unsigned short* __restrict__ W1,
    unsigned short* __restrict__ W2)
{
  const int bid = blockIdx.x;
  const int tid = threadIdx.x;
  if (bid < 16384) {
    // U[b] = [X | S | A] bf16
    int idx = bid * 256 + tid;
    int b  = idx >> 8;
    int c8 = (idx & 255) << 3;
    const float* src = (c8 < 1024) ? X + (size_t)b * 1024 + c8
                     : (c8 < 1536) ? S + (size_t)b * 512 + (c8 - 1024)
                                   : A + (size_t)b * 512 + (c8 - 1536);
    f32x4 lo = *(const f32x4*)src;
    f32x4 hi = *(const f32x4*)(src + 4);
    ushort8 o;
    o[0] = f2bf(lo[0]); o[1] = f2bf(lo[1]); o[2] = f2bf(lo[2]); o[3] = f2bf(lo[3]);
    o[4] = f2bf(hi[0]); o[5] = f2bf(hi[1]); o[6] = f2bf(hi[2]); o[7] = f2bf(hi[3]);
    *(ushort8*)&U[(size_t)b * 2048 + c8] = o;
  } else if (bid < 18432) {
    // W1 row n: [Wx{g} | Wh{g} | Vh{g}] (h-gate S/A region zero)
    int idx = (bid - 16384) * 256 + tid;
    int n  = idx >> 8;
    int k8 = (idx & 255) << 3;
    int g = n >> 9, j = n & 511;
    const float* src = nullptr;
    if (k8 < 1024) {
      const float* x = (g == 0) ? xr : (g == 1) ? xp : (g == 2) ? xz : xh;
      src = x + (size_t)j * 1024 + k8;
    } else if (k8 < 1536) {
      if (g < 3) { const float* h = (g == 0) ? hr : (g == 1) ? hp : hz; src = h + (size_t)j * 512 + (k8 - 1024); }
    } else {
      if (g < 3) { const float* v = (g == 0) ? vr : (g == 1) ? vp : vz; src = v + (size_t)j * 512 + (k8 - 1536); }
    }
    ushort8 o;
    if (src) { for (int i = 0; i < 8; i++) o[i] = f2bf(src[i]); }
    else     { for (int i = 0; i < 8; i++) o[i] = 0; }
    *(ushort8*)&W1[(size_t)n * 2048 + k8] = o;
  } else {
    // W2 = [Whh | Vhh]
    int idx = (bid - 18432) * 256 + tid;
    int n  = idx >> 7;
    int k8 = (idx & 127) << 3;
    const float* src = (k8 < 512) ? hh + (size_t)n * 512 + k8
                                  : vh + (size_t)n * 512 + (k8 - 512);
    ushort8 o;
    for (int i = 0; i < 8; i++) o[i] = f2bf(src[i]);
    *(ushort8*)&W2[(size_t)n * 1024 + k8] = o;
  }
}

// ---- GEMM1: 128x128, BK=64, 4 waves (2x2 of 64x64), 2-phase dbuf ----------
// 64 KiB static LDS -> 2 blocks/CU (two independent barrier domains, m114).
// Swizzle: LDS(row, slot16B) holds global (row, slot^(row&7)); pre-swizzled
// source + XOR on ds_read (conflict-free, verified).
__global__ __launch_bounds__(256, 2) void gemm128_epi1(
    const unsigned short* __restrict__ Amat,
    const unsigned short* __restrict__ Bmat,
    const int K,
    unsigned short* __restrict__ U2, unsigned short* __restrict__ Zp,
    unsigned short* __restrict__ XHp)
{
  __shared__ __align__(16) char lds[65536];   // 2 buf x (A 16K + B 16K)

  const int tid  = threadIdx.x;
  const int lane = tid & 63, wave = tid >> 6;
  const int wr = wave >> 1, wc = wave & 1;     // 2 x 2 wave grid
  const int fr = lane & 15, fq = lane >> 4;

  // XCD-chunked: XCD k owns m-panels 16k..16k+15, all 16 n-panels.
  const int k_xcd = blockIdx.x & 7;
  const int i_loc = (int)blockIdx.x >> 3;      // 0..255
  const int n0 = (i_loc & 15) * 128;
  const int m0 = (k_xcd * 16 + (i_loc >> 4)) * 128;

  // h-gate panels (ncol>=1536): W1 rows zero for k>=1024 -> truncate K.
  const int Keff = (n0 >= 1536) ? 1024 : K;
  const int NT   = Keff >> 6;                  // K-tiles of 64

  // staging: thread t covers rows (t>>3)+j*32 (j=0..3), slot (t&7)^(row&7)
  const int srow  = tid >> 3;                  // 0..31
  const int sslot = (tid & 7) ^ (srow & 7);
  const unsigned short* gA = Amat + (size_t)(m0 + srow) * K + sslot * 8;
  const unsigned short* gB = Bmat + (size_t)(n0 + srow) * K + sslot * 8;
  const size_t K32 = (size_t)32 * K;

  // ds_read swizzle offsets (fragment rows have row&7 == fr&7)
  int swz[2];
  swz[0] = ((fq    ) ^ (fr & 7)) << 4;
  swz[1] = ((fq + 4) ^ (fr & 7)) << 4;
  const int aoff = (wr * 64 + fr) * 128;             // + mt*2048 + swz
  const int boff = 16384 + (wc * 64 + fr) * 128;     // + nt*2048 + swz

  f32x4 acc[4][4] = {};

  auto STAGE = [&](int buf, int tile) {   // 8 gload_lds16 per thread
    const int bufo = buf << 15;
#pragma unroll
    for (int j = 0; j < 4; j++) {
      gload_lds16(gA + (size_t)j * K32 + (tile << 6), lds + bufo + j * 4096 + tid * 16);
      gload_lds16(gB + (size_t)j * K32 + (tile << 6), lds + bufo + 16384 + j * 4096 + tid * 16);
    }
  };
  auto COMPUTE = [&](int buf) {
    const int bufo = buf << 15;
    short8 b[4][2], a[4][2];
#pragma unroll
    for (int nt = 0; nt < 4; nt++)
#pragma unroll
      for (int ks = 0; ks < 2; ks++)
        b[nt][ks] = *(const short8*)(lds + bufo + boff + nt * 2048 + swz[ks]);
#pragma unroll
    for (int mt = 0; mt < 4; mt++)
#pragma unroll
      for (int ks = 0; ks < 2; ks++)
        a[mt][ks] = *(const short8*)(lds + bufo + aoff + mt * 2048 + swz[ks]);
#pragma unroll
    for (int mt = 0; mt < 4; mt++)
#pragma unroll
      for (int nt = 0; nt < 4; nt++)
#pragma unroll
        for (int ks = 0; ks < 2; ks++)
          acc[mt][nt] = __builtin_amdgcn_mfma_f32_16x16x32_bf16(
              a[mt][ks], b[nt][ks], acc[mt][nt], 0, 0, 0);
  };

  // prologue
  STAGE(0, 0);
  __syncthreads();

  int cur = 0;
  for (int t = 0; t < NT - 1; ++t) {
    STAGE(cur ^ 1, t + 1);               // next-tile DMA overlaps compute
    COMPUTE(cur);
    __syncthreads();
    cur ^= 1;
  }
  COMPUTE(cur);

  // ---- epilogue: fused gate split; S/A read as bf16 from U columns ----
#pragma unroll
  for (int mt = 0; mt < 4; mt++) {
#pragma unroll
    for (int nt = 0; nt < 4; nt++) {
      const int ncol = n0 + wc * 64 + nt * 16 + fr;
      const int gate = ncol >> 9, j = ncol & 511;
#pragma unroll
      for (int jj = 0; jj < 4; jj++) {
        const size_t rb = (size_t)(m0 + wr * 64 + mt * 16 + fq * 4 + jj);
        const float v = acc[mt][nt][jj];
        if (gate == 0) {
          const float s = bf2f(Amat[rb * 2048 + 1024 + j]);   // S (bf16, in U)
          U2[rb * 1024 + j] = f2bf(sigm(v) * s);
        } else if (gate == 1) {
          const float a2 = bf2f(Amat[rb * 2048 + 1536 + j]);  // A (bf16, in U)
          U2[rb * 1024 + 512 + j] = f2bf(sigm(v) * a2);
        } else if (gate == 2) {
          Zp[rb * 512 + j]  = f2bf(v);
        } else {
          XHp[rb * 512 + j] = f2bf(v);
        }
      }
    }
  }
}

// ---- GEMM2: 256x128, BK=64, 8 waves (4Mx2N), 2-phase dbuf, 1 blk/CU -------
__global__ __launch_bounds__(512, 1) void gemm2_fin(
    const unsigned short* __restrict__ U2,     // A: B x 1024
    const unsigned short* __restrict__ W2,     // B: 512 x 1024
    const unsigned short* __restrict__ Uu,     // U (S bf16 at cols 1024..1535)
    const unsigned short* __restrict__ Zp,
    const unsigned short* __restrict__ XHp, float* __restrict__ Out)
{
  extern __shared__ char lds[];
  constexpr int K = 1024, NT = K >> 6;

  const int tid  = threadIdx.x;
  const int lane = tid & 63, wave = tid >> 6;
  const int wm = wave >> 1, wn = wave & 1;     // 4 x 2 wave grid
  const int fr = lane & 15, fq = lane >> 4;

  const int k_xcd = blockIdx.x & 7;
  const int i_loc = (int)blockIdx.x >> 3;      // 0..31
  const int n0 = (i_loc & 3) * 128;
  const int m0 = (k_xcd * 8 + (i_loc >> 2)) * 256;

  const int srow  = tid >> 3;
  const int sslot = (tid & 7) ^ (srow & 7);
  const unsigned short* gA = U2 + (size_t)(m0 + srow) * K + sslot * 8;
  const unsigned short* gB = W2 + (size_t)(n0 + srow) * K + sslot * 8;
  const size_t K64 = (size_t)64 * K;

  int swz[2];
  swz[0] = ((fq    ) ^ (fr & 7)) << 4;
  swz[1] = ((fq + 4) ^ (fr & 7)) << 4;
  const int aoff = wm * 8192 + fr * 128;
  const int boff = 32768 + wn * 8192 + fr * 128;

  f32x4 acc[4][4] = {};

  auto STAGE = [&](int buf, int tile) {
    const int bufo = buf * 49152;
#pragma unroll
    for (int j = 0; j < 4; j++)
      gload_lds16(gA + (size_t)j * K64 + (tile << 6), lds + bufo + tid * 16 + j * 8192);
#pragma unroll
    for (int j = 0; j < 2; j++)
      gload_lds16(gB + (size_t)j * K64 + (tile << 6), lds + bufo + 32768 + tid * 16 + j * 8192);
  };
  auto COMPUTE = [&](int buf) {
    const int bufo = buf * 49152;
    short8 b[4][2];
#pragma unroll
    for (int ni = 0; ni < 4; ni++)
#pragma unroll
      for (int ks = 0; ks < 2; ks++)
        b[ni][ks] = *(const short8*)(lds + bufo + boff + ni * 2048 + swz[ks]);
#pragma unroll
    for (int c = 0; c < 2; c++) {
      short8 a[2][2];
#pragma unroll
      for (int i = 0; i < 2; i++)
#pragma unroll
        for (int ks = 0; ks < 2; ks++)
          a[i][ks] = *(const short8*)(lds + bufo + aoff + (c * 2 + i) * 2048 + swz[ks]);
#pragma unroll
      for (int i = 0; i < 2; i++)
#pragma unroll
        for (int ni = 0; ni < 4; ni++)
#pragma unroll
          for (int ks = 0; ks < 2; ks++)
            acc[c * 2 + i][ni] = __builtin_amdgcn_mfma_f32_16x16x32_bf16(
                a[i][ks], b[ni][ks], acc[c * 2 + i][ni], 0, 0, 0);
    }
  };

  STAGE(0, 0);
  __syncthreads();

  int cur = 0;
  for (int t = 0; t < NT - 1; ++t) {
    STAGE(cur ^ 1, t + 1);
    COMPUTE(cur);
    __syncthreads();
    cur ^= 1;
  }
  COMPUTE(cur);

#pragma unroll
  for (int mt = 0; mt < 4; mt++) {
#pragma unroll
    for (int nt = 0; nt < 4; nt++) {
      const int ncol = n0 + wn * 64 + nt * 16 + fr;
#pragma unroll
      for (int jj = 0; jj < 4; jj++) {
        const size_t rb = (size_t)(m0 + wm * 64 + mt * 16 + fq * 4 + jj);
        const size_t o = rb * 512 + ncol;
        const float z = sigm(bf2f(Zp[o]));
        const float h = tanh_fast(bf2f(XHp[o]) + acc[mt][nt][jj]);
        const float s = bf2f(Uu[rb * 2048 + 1024 + ncol]);
        Out[o] = (1.0f - z) * s + z * h;
      }
    }
  }
}

// ---------------------------------------------------------------------------

extern "C" void kernel_launch(void* const* d_in, const int* in_sizes, int n_in,
                              void* d_out, int out_size, void* d_ws, size_t ws_size,
                              hipStream_t stream) {
  const float* X   = (const float*)d_in[0];
  const float* S   = (const float*)d_in[1];
  const float* A   = (const float*)d_in[2];
  const float* Wxr = (const float*)d_in[3];
  const float* Wxp = (const float*)d_in[4];
  const float* Wxz = (const float*)d_in[5];
  const float* Wxh = (const float*)d_in[6];
  const float* Whr = (const float*)d_in[7];
  const float* Whp = (const float*)d_in[8];
  const float* Whz = (const float*)d_in[9];
  const float* Whh = (const float*)d_in[10];
  const float* Vhr = (const float*)d_in[11];
  const float* Vhp = (const float*)d_in[12];
  const float* Vhz = (const float*)d_in[13];
  const float* Vhh = (const float*)d_in[14];

  char* ws = (char*)d_ws;
  size_t off = 0;
  auto alloc = [&](size_t bytes) -> void* {
    void* p = ws + off;
    off += (bytes + 255) & ~(size_t)255;
    return p;
  };
  unsigned short* W1 = (unsigned short*)alloc((size_t)2048 * 2048 * 2);
  unsigned short* W2 = (unsigned short*)alloc((size_t)512 * 1024 * 2);
  unsigned short* U  = (unsigned short*)alloc((size_t)Bn * 2048 * 2);
  unsigned short* U2 = (unsigned short*)alloc((size_t)Bn * 1024 * 2);
  unsigned short* Zp = (unsigned short*)alloc((size_t)Bn * 512 * 2);
  unsigned short* XH = (unsigned short*)alloc((size_t)Bn * 512 * 2);

  // all packing in ONE dispatch: U (16384) | W1 (2048) | W2 (256)
  pack_all<<<18688, 256, 0, stream>>>(
      X, S, A, Wxr, Wxp, Wxz, Wxh, Whr, Whp, Whz, Vhr, Vhp, Vhz,
      Whh, Vhh, U, W1, W2);

  (void)hipFuncSetAttribute((const void*)gemm2_fin,
                            hipFuncAttributeMaxDynamicSharedMemorySize, 98304);

  // GEMM1: P = U(16384x2048) @ W1^T(2048x2048), gate epilogue.
  // Grid 2048 = 8 XCD x (16 m-panels x 16 n-panels); 2 blocks/CU.
  gemm128_epi1<<<2048, 256, 0, stream>>>(U, W1, 2048, U2, Zp, XH);

  // GEMM2: U2(16384x1024) @ W2^T(512x1024), final epilogue -> d_out.
  gemm2_fin<<<256, 512, 98304, stream>>>(U2, W2, U, Zp, XH, (float*)d_out);
}